// Round 15
// baseline (191.071 us; speedup 1.0000x reference)
//
#include <hip/hip_runtime.h>

// ---------------------------------------------------------------------------
// LocalWindowAttentionLayer on MI355X (gfx950)
// B=4 L=2048 D=512 H=8 DK=64 DF=2048 W=9
//
// Pipeline (G2 folded into G1 via Wvo = Wv@Wo):
//  prep: transposes + bias + x->bf16 in ONE dispatch
//  Wvo: WvoT = gemm(WoT, Wvb)
//  G1 : QKV'' = xb @ [Wq;Wk;Wvo]^T + [bq;bk;bvo]   (8192 x 1536, K=512)
//  A  : banded-Gram attention -> newx (8192 x 512)
//  LN1: x1 = LN(xb + newx)
//  G3 : h = gelu(x1 @ W1T^T + b1)       (8192 x 2048, K=512)  [fast gelu]
//  G4 : y partials (split-K=2)          (8192 x 512,  K=2048)
//  LN2: out = LN(x1 + y0 + y1 + b2) -> fp32
//
// gemm (R15 = R13 + B-direct): B matrices are L2-resident (<=2MB) — their
// LDS round-trip is pure staging-path waste. A keeps the R13-proven path
// (BK=64, 4 gload_lds/thread, granule permute, 2-buf, stage(t+1)-before-
// compute, vmcnt(0)+barrier per tile). B fragments now load DIRECTLY
// global->VGPR with a register double-buffer: B(t+1) issued right after
// A-stage(t+1), covered by compute, retired by the same end-of-tile
// vmcnt(0). Staged bytes: G3 393->268MB, G4 402->268MB, G1 300->201MB.
// LDS 48->32KB; ~100 VGPR; launch_bounds(256,3).
// ---------------------------------------------------------------------------

typedef unsigned short u16;
typedef __attribute__((ext_vector_type(8))) short short8;   // 8 bf16
typedef __attribute__((ext_vector_type(4))) float floatx4;  // MFMA acc

#define DEV static __device__ __forceinline__

DEV float b2f(u16 u) {
  union { unsigned int i; float f; } x; x.i = ((unsigned int)u) << 16; return x.f;
}
DEV u16 f2b(float f) {  // round-to-nearest-even
  union { float f; unsigned int i; } x; x.f = f;
  unsigned int u = x.i + 0x7fffu + ((x.i >> 16) & 1u);
  return (u16)(u >> 16);
}

#define AS1 __attribute__((address_space(1)))
#define AS3 __attribute__((address_space(3)))
DEV void gload_lds16(const void* g, void* l) {
  __builtin_amdgcn_global_load_lds((const AS1 void*)g, (AS3 void*)l, 16, 0, 0);
}

// ---------------------------------------------------------------------------
// Fused prep, one dispatch:
//  [0,3072)    : transposes (fp32 RxC -> bf16 CxR) Wq,Wk,Wo,W1,W2 + Wv copy
//  [3072,3080) : bias vector prep (bq | bk | bvo = bv@Wo | zeros)
//  [3080,7176) : x fp32 -> bf16 (float4 granules)
// ---------------------------------------------------------------------------
__global__ __launch_bounds__(256) void prep_all(
    const float* __restrict__ Wq, const float* __restrict__ Wk,
    const float* __restrict__ Wo, const float* __restrict__ W1,
    const float* __restrict__ W2, const float* __restrict__ Wv,
    const float* __restrict__ bq, const float* __restrict__ bk,
    const float* __restrict__ bv, const float* __restrict__ x,
    u16* __restrict__ WqkvT, u16* __restrict__ WoT,
    u16* __restrict__ W1T, u16* __restrict__ W2T, u16* __restrict__ Wvb,
    float* __restrict__ bqkv, u16* __restrict__ xb) {
  const int bid = blockIdx.x;
  if (bid >= 3080) {  // x f2b
    const int i = (bid - 3080) * 256 + threadIdx.x;
    float4 v = ((const float4*)x)[i];
    ushort4 o;
    o.x = f2b(v.x); o.y = f2b(v.y); o.z = f2b(v.z); o.w = f2b(v.w);
    ((ushort4*)xb)[i] = o;
    return;
  }
  if (bid >= 3072) {  // bias prep
    const int i = (bid - 3072) * 256 + threadIdx.x;
    if (i < 512) bqkv[i] = bq[i];
    else if (i < 1024) bqkv[i] = bk[i - 512];
    else if (i < 1536) {
      const int c = i - 1024;
      float s = 0.f;
      for (int j = 0; j < 512; ++j) s += bv[j] * Wo[(size_t)j * 512 + c];
      bqkv[i] = s;
    } else bqkv[i] = 0.f;
    return;
  }
  if (bid >= 2816) {  // Wv f2b copy (512x512)
    const int i = (bid - 2816) * 256 + threadIdx.x;
    float4 v = ((const float4*)Wv)[i];
    ushort4 o;
    o.x = f2b(v.x); o.y = f2b(v.y); o.z = f2b(v.z); o.w = f2b(v.w);
    ((ushort4*)Wvb)[i] = o;
    return;
  }
  const float* in; u16* out; int R, C, t;
  if (bid < 256)       { in = Wq; out = WqkvT;          R = 512;  C = 512;  t = bid; }
  else if (bid < 512)  { in = Wk; out = WqkvT + 262144; R = 512;  C = 512;  t = bid - 256; }
  else if (bid < 768)  { in = Wo; out = WoT;            R = 512;  C = 512;  t = bid - 512; }
  else if (bid < 1792) { in = W1; out = W1T;            R = 512;  C = 2048; t = bid - 768; }
  else                 { in = W2; out = W2T;            R = 2048; C = 512;  t = bid - 1792; }
  const int tpr = C >> 5;
  const int bc = (t % tpr) * 32, br = (t / tpr) * 32;
  __shared__ float tile[32][33];
  const int tx = threadIdx.x & 31, ty = threadIdx.x >> 5;
  #pragma unroll
  for (int i = 0; i < 32; i += 8)
    tile[ty + i][tx] = in[(size_t)(br + ty + i) * C + bc + tx];
  __syncthreads();
  #pragma unroll
  for (int i = 0; i < 32; i += 8)
    out[(size_t)(bc + ty + i) * R + br + tx] = f2b(tile[tx][ty + i]);
}

// ---------------------------------------------------------------------------
// bf16 MFMA GEMM, BK=64, A via LDS (R13 path), B direct global->VGPR.
// C = A[M][lda] @ BT[N][lda]^T + bias
// EPI: 0=bias->bf16, 1=bias+fast-gelu->bf16, 2=raw bf16 partial (split-K z)
// BM=128, BN=64; 256 thr = 4 waves (wr=w&1, wc=w>>1), wave 64x32, acc[4][2].
// LDS: As[2][8192] = 32KB (A only).
// ---------------------------------------------------------------------------
template<int EPI>
__global__ __launch_bounds__(256, 3) void gemm_bt(
    const u16* __restrict__ A, const u16* __restrict__ BT,
    const float* __restrict__ bias, u16* __restrict__ C, u16* __restrict__ C2,
    int M, int N, int lda, int kb) {
  __shared__ __align__(16) u16 As[2][8192];
  const int tid = threadIdx.x;
  const int w = tid >> 6, l = tid & 63;
  const int l15 = l & 15, l4 = l >> 4;
  const int wr = w & 1, wc = w >> 1;

  // T1: XCD-chunked swizzle over flattened 3D grid (guard nwg%8)
  const int gx = (int)gridDim.x, gy = (int)gridDim.y;
  int id = ((int)blockIdx.z * gy + (int)blockIdx.y) * gx + (int)blockIdx.x;
  const int nwg = gx * gy * (int)gridDim.z;
  if ((nwg & 7) == 0) { const int cpx = nwg >> 3; id = (id & 7) * cpx + (id >> 3); }
  const int bx = id % gx; const int r1 = id / gx;
  const int by = r1 % gy; const int bz = r1 / gy;
  const int bm = by * 128, bn = bx * 64;
  const int koff = bz * kb;

  // A staging (R13-verified): srow = tid>>3 in [0,32), permuted source granule
  const int srow = tid >> 3;
  const int sg8 = (((tid & 7) - (srow & 7)) & 7) * 8;
  const u16* gA = A + (size_t)(bm + srow) * lda + koff + sg8;
  const size_t r32 = (size_t)32 * lda;
  const int sd = tid * 8;

  // A fragment read offsets: row r, logical granule l4+4*kh at phys (lg+(r&7))&7
  int aOff[2][4];
  #pragma unroll
  for (int kh = 0; kh < 2; ++kh)
    #pragma unroll
    for (int m = 0; m < 4; ++m) {
      const int r = wr * 64 + m * 16 + l15;
      aOff[kh][m] = r * 64 + (((l4 + 4 * kh) + (r & 7)) & 7) * 8;
    }

  // B direct per-lane base: row (bn + wc*32 + l15), k-offset l4*8
  const u16* pB = BT + (size_t)(bn + wc * 32 + l15) * lda + koff + l4 * 8;
  const size_t bn16 = (size_t)16 * lda;   // n-fragment stride (16 B-rows)

  floatx4 acc[4][2] = {};
  const int nt = kb >> 6;

  auto stageA = [&](int t, int buf) {
    const u16* a = gA + (size_t)t * 64;
    gload_lds16(a,           &As[buf][sd]);
    gload_lds16(a + r32,     &As[buf][2048 + sd]);
    gload_lds16(a + 2 * r32, &As[buf][4096 + sd]);
    gload_lds16(a + 3 * r32, &As[buf][6144 + sd]);
  };

  // B register double-buffer: [kh][n] as named vars (static indexing)
  short8 b00, b01, b10, b11, n00, n01, n10, n11;
  b00 = *(const short8*)(pB);
  b01 = *(const short8*)(pB + bn16);
  b10 = *(const short8*)(pB + 32);
  b11 = *(const short8*)(pB + bn16 + 32);

  stageA(0, 0);
  asm volatile("s_waitcnt vmcnt(0)" ::: "memory");
  __builtin_amdgcn_s_barrier();
  asm volatile("" ::: "memory");

  for (int t = 0; t < nt; ++t) {
    const int cur = t & 1;
    const bool pf = (t + 1 < nt);
    if (pf) {
      stageA(t + 1, cur ^ 1);
      const u16* pb = pB + (size_t)(t + 1) * 64;
      n00 = *(const short8*)(pb);
      n01 = *(const short8*)(pb + bn16);
      n10 = *(const short8*)(pb + 32);
      n11 = *(const short8*)(pb + bn16 + 32);
    }

    {
      short8 af[4];
      #pragma unroll
      for (int m = 0; m < 4; ++m) af[m] = *(const short8*)(&As[cur][aOff[0][m]]);
      #pragma unroll
      for (int m = 0; m < 4; ++m) {
        acc[m][0] = __builtin_amdgcn_mfma_f32_16x16x32_bf16(af[m], b00, acc[m][0], 0, 0, 0);
        acc[m][1] = __builtin_amdgcn_mfma_f32_16x16x32_bf16(af[m], b01, acc[m][1], 0, 0, 0);
      }
    }
    {
      short8 af[4];
      #pragma unroll
      for (int m = 0; m < 4; ++m) af[m] = *(const short8*)(&As[cur][aOff[1][m]]);
      #pragma unroll
      for (int m = 0; m < 4; ++m) {
        acc[m][0] = __builtin_amdgcn_mfma_f32_16x16x32_bf16(af[m], b10, acc[m][0], 0, 0, 0);
        acc[m][1] = __builtin_amdgcn_mfma_f32_16x16x32_bf16(af[m], b11, acc[m][1], 0, 0, 0);
      }
    }

    asm volatile("s_waitcnt vmcnt(0)" ::: "memory");
    __builtin_amdgcn_s_barrier();
    asm volatile("" ::: "memory");

    if (pf) { b00 = n00; b01 = n01; b10 = n10; b11 = n11; }
  }

  // ---- epilogue ----
  const int col0 = bn + wc * 32 + l15;
  if (EPI <= 1) {
    float bvv[2];
    #pragma unroll
    for (int n = 0; n < 2; ++n) bvv[n] = bias[col0 + n * 16];
    #pragma unroll
    for (int m = 0; m < 4; ++m) {
      #pragma unroll
      for (int ri = 0; ri < 4; ++ri) {
        const size_t row = (size_t)(bm + wr * 64 + m * 16 + l4 * 4 + ri);
        u16* cp = C + row * N + col0;
        #pragma unroll
        for (int n = 0; n < 2; ++n) {
          float vv = acc[m][n][ri] + bvv[n];
          if (EPI == 1) {
            // fast gelu: v * sigmoid(1.5957691 * (v + 0.044715 v^3))
            const float u = vv * (1.0f + 0.044715f * vv * vv);
            vv = vv / (1.0f + __expf(-1.5957691216057308f * u));
          }
          cp[n * 16] = f2b(vv);
        }
      }
    }
  } else {
    u16* o = (bz == 0) ? C : C2;
    #pragma unroll
    for (int m = 0; m < 4; ++m) {
      #pragma unroll
      for (int ri = 0; ri < 4; ++ri) {
        const size_t row = (size_t)(bm + wr * 64 + m * 16 + l4 * 4 + ri);
        u16* cp = o + row * N + col0;
        #pragma unroll
        for (int n = 0; n < 2; ++n) cp[n * 16] = f2b(acc[m][n][ri]);
      }
    }
  }
}

// ---------------------------------------------------------------------------
// Banded-Gram attention. One block per (b, 32-pos chunk, head).
// ---------------------------------------------------------------------------
#define ATL 32
#define ART (ATL + 8)   // 40 staged rows

__global__ __launch_bounds__(256) void attn_band(
    const u16* __restrict__ QKV, const float* __restrict__ bqkv,
    const float* __restrict__ bo, u16* __restrict__ newx) {
  __shared__ __align__(16) u16 S3[3][ART][72];
  __shared__ float Gb[ART][18];
  __shared__ float Sm[ART][81];
  __shared__ float Wb[ATL][9];

  const int tid = threadIdx.x;
  const int bid = ((int)blockIdx.x & 7) * 256 + ((int)blockIdx.x >> 3);
  const int h = bid & 7;
  const int chunk = (bid >> 3) & 63;
  const int b = bid >> 9;
  const int l0 = chunk * ATL;

  for (int idx = tid; idx < ART * 24; idx += 256) {
    const int ti = idx / 24, c = idx % 24;
    const int slice = c >> 3, d8 = (c & 7) * 8;
    const int col = slice * 512 + h * 64 + d8;
    const int t = l0 - 4 + ti;
    short8 v;
    if ((unsigned)t < 2048u) {
      v = *(const short8*)(QKV + ((size_t)((b << 11) | t)) * 1536 + col);
    } else {
      #pragma unroll
      for (int j = 0; j < 8; ++j) v[j] = (short)f2b(bqkv[col + j]);
    }
    *(short8*)(&S3[slice][ti][d8]) = v;
  }
  __syncthreads();

  for (int task = tid; task < ART * 17; task += 256) {
    const int ti = task / 17, j = task % 17;
    const int ui = ti + j - 8;
    if ((unsigned)ui < (unsigned)ART) {
      float a = 0.f;
      #pragma unroll
      for (int d0 = 0; d0 < 64; d0 += 8) {
        short8 qv = *(const short8*)(&S3[0][ti][d0]);
        short8 kv = *(const short8*)(&S3[1][ui][d0]);
        #pragma unroll
        for (int jj = 0; jj < 8; ++jj) a += b2f((u16)qv[jj]) * b2f((u16)kv[jj]);
      }
      Gb[ti][j] = a * 0.125f;
    }
  }
  __syncthreads();

  for (int task = tid; task < ART * 9; task += 256) {
    const int ti = task / 9, qw = task % 9;
    const int li = ti - qw;
    if ((unsigned)li < (unsigned)ATL) {
      float m = -1e30f;
      #pragma unroll
      for (int kw = 0; kw < 9; ++kw) m = fmaxf(m, Gb[ti][kw - qw + 8]);
      float e[9], s = 0.f;
      #pragma unroll
      for (int kw = 0; kw < 9; ++kw) { e[kw] = expf(Gb[ti][kw - qw + 8] - m); s += e[kw]; }
      const float inv = 1.f / s;
      #pragma unroll
      for (int kw = 0; kw < 9; ++kw) Sm[ti][qw * 9 + kw] = e[kw] * inv;
    }
  }
  __syncthreads();

  for (int task = tid; task < ATL * 9; task += 256) {
    const int li = task / 9, kw = task % 9;
    float s = 0.f;
    #pragma unroll
    for (int qw = 0; qw < 9; ++qw) s += Sm[li + qw][qw * 9 + kw];
    Wb[li][kw] = s * (1.f / 9.f);
  }
  __syncthreads();

  {
    const int li = tid >> 3, d8 = (tid & 7) * 8;
    float w[9];
    #pragma unroll
    for (int kw = 0; kw < 9; ++kw) w[kw] = Wb[li][kw];
    float a[8] = {};
    #pragma unroll
    for (int kw = 0; kw < 9; ++kw) {
      short8 vv = *(const short8*)(&S3[2][li + kw][d8]);
      #pragma unroll
      for (int jj = 0; jj < 8; ++jj) a[jj] += w[kw] * b2f((u16)vv[jj]);
    }
    short8 o;
    #pragma unroll
    for (int jj = 0; jj < 8; ++jj) o[jj] = (short)f2b(a[jj] + bo[h * 64 + d8 + jj]);
    const int l = l0 + li;
    *(short8*)(newx + ((size_t)((b << 11) | l)) * 512 + h * 64 + d8) = o;
  }
}

// ---------------------------------------------------------------------------
// LayerNorm over D=512. One wave per row, 4 rows/block.
// MODE 0: v = a + b                  -> bf16 out
// MODE 1: v = a + b + c + bias[col]  -> fp32 out
// ---------------------------------------------------------------------------
template<int MODE>
__global__ __launch_bounds__(256) void ln_kernel(
    const u16* __restrict__ a, const u16* __restrict__ bsrc,
    const u16* __restrict__ csrc, const float* __restrict__ bias,
    const float* __restrict__ g, const float* __restrict__ be,
    u16* __restrict__ outb, float* __restrict__ outf) {
  const int wave = threadIdx.x >> 6, lane = threadIdx.x & 63;
  const size_t row = (size_t)blockIdx.x * 4 + wave;
  const size_t base = row * 512 + lane * 8;
  const int gi = lane * 8;
  float v[8];
  short8 a8 = *(const short8*)(a + base);
  short8 b8 = *(const short8*)(bsrc + base);
  #pragma unroll
  for (int j = 0; j < 8; ++j) v[j] = b2f((u16)a8[j]) + b2f((u16)b8[j]);
  if (MODE == 1) {
    short8 c8 = *(const short8*)(csrc + base);
    #pragma unroll
    for (int j = 0; j < 8; ++j) v[j] += b2f((u16)c8[j]) + bias[gi + j];
  }

  float s = 0.f;
  #pragma unroll
  for (int j = 0; j < 8; ++j) s += v[j];
  #pragma unroll
  for (int off = 32; off >= 1; off >>= 1) s += __shfl_xor(s, off, 64);
  const float mean = s * (1.f / 512.f);
  float sq = 0.f;
  #pragma unroll
  for (int j = 0; j < 8; ++j) { float d = v[j] - mean; sq += d * d; }
  #pragma unroll
  for (int off = 32; off >= 1; off >>= 1) sq += __shfl_xor(sq, off, 64);
  const float rs = rsqrtf(sq * (1.f / 512.f) + 1e-5f);

  if (MODE == 0) {
    short8 o;
    #pragma unroll
    for (int j = 0; j < 8; ++j)
      o[j] = (short)f2b((v[j] - mean) * rs * g[gi + j] + be[gi + j]);
    *(short8*)(outb + base) = o;
  } else {
    float4 o0, o1;
    o0.x = (v[0] - mean) * rs * g[gi + 0] + be[gi + 0];
    o0.y = (v[1] - mean) * rs * g[gi + 1] + be[gi + 1];
    o0.z = (v[2] - mean) * rs * g[gi + 2] + be[gi + 2];
    o0.w = (v[3] - mean) * rs * g[gi + 3] + be[gi + 3];
    o1.x = (v[4] - mean) * rs * g[gi + 4] + be[gi + 4];
    o1.y = (v[5] - mean) * rs * g[gi + 5] + be[gi + 5];
    o1.z = (v[6] - mean) * rs * g[gi + 6] + be[gi + 6];
    o1.w = (v[7] - mean) * rs * g[gi + 7] + be[gi + 7];
    *(float4*)(outf + base) = o0;
    *(float4*)(outf + base + 4) = o1;
  }
}

// ---------------------------------------------------------------------------
extern "C" void kernel_launch(void* const* d_in, const int* in_sizes, int n_in,
                              void* d_out, int out_size, void* d_ws, size_t ws_size,
                              hipStream_t stream) {
  const float* x   = (const float*)d_in[0];
  const float* Wq  = (const float*)d_in[1];
  const float* bq  = (const float*)d_in[2];
  const float* Wk  = (const float*)d_in[3];
  const float* bk  = (const float*)d_in[4];
  const float* Wv  = (const float*)d_in[5];
  const float* bv  = (const float*)d_in[6];
  const float* Wo  = (const float*)d_in[7];
  const float* bo  = (const float*)d_in[8];
  const float* W1  = (const float*)d_in[9];
  const float* b1  = (const float*)d_in[10];
  const float* W2  = (const float*)d_in[11];
  const float* b2  = (const float*)d_in[12];
  const float* g1  = (const float*)d_in[13];
  const float* be1 = (const float*)d_in[14];
  const float* g2  = (const float*)d_in[15];
  const float* be2 = (const float*)d_in[16];

  char* w = (char*)d_ws;
  u16*   xb    = (u16*)  (w + 0);           // 8 MB; yp1 after LN1
  u16*   WqkvT = (u16*)  (w + 8388608);     // [1536][512] bf16 (q,k,vo)
  u16*   WoT   = (u16*)  (w + 9961472);     // [512][512] bf16 Wo^T
  u16*   W1T   = (u16*)  (w + 10485760);    // [2048][512]
  u16*   W2T   = (u16*)  (w + 12582912);    // [512][2048]
  float* bqkv  = (float*)(w + 14680064);    // 2048 f32 (bq,bk,bvo,zeros)
  u16*   Wvb   = (u16*)  (w + 14688256);    // [512][512] bf16 row-major Wv
  u16*   QKV   = (u16*)  (w + 15212544);    // 8192x1536 bf16 (dead after attn)
  u16*   hbuf  = QKV;                       // 8192x2048 bf16 (aliases QKV)
  u16*   newx  = (u16*)  (w + 48766976);    // 8192x512 bf16; yp0 after LN1
  u16*   x1b   = (u16*)  (w + 57155584);    // 8192x512 bf16
  u16*   WvoT  = WqkvT + 524288;            // V region of WqkvT = (Wv@Wo)^T
  u16*   yp0   = newx;                      // G4 split-K partial z=0
  u16*   yp1   = xb;                        // G4 split-K partial z=1

  // --- prep (single dispatch: transposes + bias + x->bf16) ---
  prep_all<<<7176, 256, 0, stream>>>(Wq, Wk, Wo, W1, W2, Wv, bq, bk, bv, x,
                                     WqkvT, WoT, W1T, W2T, Wvb, bqkv, xb);
  // --- WvoT = (Wv@Wo)^T via MFMA GEMM: C[n][k] = sum_j WoT[n][j]*Wvb[k][j] ---
  gemm_bt<0><<<dim3(8, 4, 1), 256, 0, stream>>>(WoT, Wvb, bqkv + 1536, WvoT, nullptr,
                                                512, 512, 512, 512);
  // --- G1: QKV'' ---
  gemm_bt<0><<<dim3(24, 64, 1), 256, 0, stream>>>(xb, WqkvT, bqkv, QKV, nullptr,
                                                  8192, 1536, 512, 512);
  // --- attention (banded Gram) -> newx ---
  attn_band<<<2048, 256, 0, stream>>>(QKV, bqkv, bo, newx);
  // --- LN1: x1 = LN(xb + newx) ---
  ln_kernel<0><<<2048, 256, 0, stream>>>(xb, newx, nullptr, nullptr, g1, be1, x1b, nullptr);
  // --- G3: h = gelu(x1 @ W1T^T + b1) ---
  gemm_bt<1><<<dim3(32, 64, 1), 256, 0, stream>>>(x1b, W1T, b1, hbuf, nullptr,
                                                  8192, 2048, 512, 512);
  // --- G4: y partials (split-K=2, K=1024 each) ---
  gemm_bt<2><<<dim3(8, 64, 2), 256, 0, stream>>>(hbuf, W2T, nullptr, yp0, yp1,
                                                 8192, 512, 2048, 1024);
  // --- LN2 -> out ---
  ln_kernel<1><<<2048, 256, 0, stream>>>(x1b, yp0, yp1, b2, g2, be2, nullptr, (float*)d_out);
}

// Round 16
// 145.726 us; speedup vs baseline: 1.3112x; 1.3112x over previous
//
#include <hip/hip_runtime.h>

// ---------------------------------------------------------------------------
// LocalWindowAttentionLayer on MI355X (gfx950)  — R16 = R13 verbatim (best:
// 144.3 µs). R14 (256x128 tile) and R15 (B-direct) both regressed; the
// 2-phase BK=64 128x64 structure below is the verified local optimum.
// B=4 L=2048 D=512 H=8 DK=64 DF=2048 W=9
//
// Pipeline (G2 folded into G1 via Wvo = Wv@Wo):
//  prep: transposes + bias + x->bf16 in ONE dispatch
//  Wvo: WvoT = gemm(WoT, Wvb)
//  G1 : QKV'' = xb @ [Wq;Wk;Wvo]^T + [bq;bk;bvo]   (8192 x 1536, K=512)
//  A  : banded-Gram attention -> newx (8192 x 512)
//  LN1: x1 = LN(xb + newx)
//  G3 : h = gelu(x1 @ W1T^T + b1)       (8192 x 2048, K=512)  [fast gelu]
//  G4 : y = h @ W2T^T + b2              (8192 x 512,  K=2048)
//  LN2: out = LN(x1 + y) -> fp32
//
// gemm: BM=128 BN=64 BK=64; 4 waves (wave 64x32, 16 MFMA/tile over 2
// k-halves); LDS 2 x 24KB = 48KB -> 3 blocks/CU. stage(t+1) issued before
// the compute phase, vmcnt(0)+barrier at tile end. 8-granule XOR permute
// (conflict-free, rule-21 both-sides involution), XCD-chunked swizzle.
// ---------------------------------------------------------------------------

typedef unsigned short u16;
typedef __attribute__((ext_vector_type(8))) short short8;   // 8 bf16
typedef __attribute__((ext_vector_type(4))) float floatx4;  // MFMA acc

#define DEV static __device__ __forceinline__

DEV float b2f(u16 u) {
  union { unsigned int i; float f; } x; x.i = ((unsigned int)u) << 16; return x.f;
}
DEV u16 f2b(float f) {  // round-to-nearest-even
  union { float f; unsigned int i; } x; x.f = f;
  unsigned int u = x.i + 0x7fffu + ((x.i >> 16) & 1u);
  return (u16)(u >> 16);
}

#define AS1 __attribute__((address_space(1)))
#define AS3 __attribute__((address_space(3)))
DEV void gload_lds16(const void* g, void* l) {
  __builtin_amdgcn_global_load_lds((const AS1 void*)g, (AS3 void*)l, 16, 0, 0);
}

// ---------------------------------------------------------------------------
// Fused prep, one dispatch:
//  [0,3072)    : transposes (fp32 RxC -> bf16 CxR) Wq,Wk,Wo,W1,W2 + Wv copy
//  [3072,3080) : bias vector prep (bq | bk | bvo = bv@Wo | zeros)
//  [3080,7176) : x fp32 -> bf16 (float4 granules)
// ---------------------------------------------------------------------------
__global__ __launch_bounds__(256) void prep_all(
    const float* __restrict__ Wq, const float* __restrict__ Wk,
    const float* __restrict__ Wo, const float* __restrict__ W1,
    const float* __restrict__ W2, const float* __restrict__ Wv,
    const float* __restrict__ bq, const float* __restrict__ bk,
    const float* __restrict__ bv, const float* __restrict__ x,
    u16* __restrict__ WqkvT, u16* __restrict__ WoT,
    u16* __restrict__ W1T, u16* __restrict__ W2T, u16* __restrict__ Wvb,
    float* __restrict__ bqkv, u16* __restrict__ xb) {
  const int bid = blockIdx.x;
  if (bid >= 3080) {  // x f2b
    const int i = (bid - 3080) * 256 + threadIdx.x;
    float4 v = ((const float4*)x)[i];
    ushort4 o;
    o.x = f2b(v.x); o.y = f2b(v.y); o.z = f2b(v.z); o.w = f2b(v.w);
    ((ushort4*)xb)[i] = o;
    return;
  }
  if (bid >= 3072) {  // bias prep
    const int i = (bid - 3072) * 256 + threadIdx.x;
    if (i < 512) bqkv[i] = bq[i];
    else if (i < 1024) bqkv[i] = bk[i - 512];
    else if (i < 1536) {
      const int c = i - 1024;
      float s = 0.f;
      for (int j = 0; j < 512; ++j) s += bv[j] * Wo[(size_t)j * 512 + c];
      bqkv[i] = s;
    } else bqkv[i] = 0.f;
    return;
  }
  if (bid >= 2816) {  // Wv f2b copy (512x512)
    const int i = (bid - 2816) * 256 + threadIdx.x;
    float4 v = ((const float4*)Wv)[i];
    ushort4 o;
    o.x = f2b(v.x); o.y = f2b(v.y); o.z = f2b(v.z); o.w = f2b(v.w);
    ((ushort4*)Wvb)[i] = o;
    return;
  }
  const float* in; u16* out; int R, C, t;
  if (bid < 256)       { in = Wq; out = WqkvT;          R = 512;  C = 512;  t = bid; }
  else if (bid < 512)  { in = Wk; out = WqkvT + 262144; R = 512;  C = 512;  t = bid - 256; }
  else if (bid < 768)  { in = Wo; out = WoT;            R = 512;  C = 512;  t = bid - 512; }
  else if (bid < 1792) { in = W1; out = W1T;            R = 512;  C = 2048; t = bid - 768; }
  else                 { in = W2; out = W2T;            R = 2048; C = 512;  t = bid - 1792; }
  const int tpr = C >> 5;
  const int bc = (t % tpr) * 32, br = (t / tpr) * 32;
  __shared__ float tile[32][33];
  const int tx = threadIdx.x & 31, ty = threadIdx.x >> 5;
  #pragma unroll
  for (int i = 0; i < 32; i += 8)
    tile[ty + i][tx] = in[(size_t)(br + ty + i) * C + bc + tx];
  __syncthreads();
  #pragma unroll
  for (int i = 0; i < 32; i += 8)
    out[(size_t)(bc + ty + i) * R + br + tx] = f2b(tile[tx][ty + i]);
}

// ---------------------------------------------------------------------------
// bf16 MFMA GEMM, BK=64, counted-overlap 2-buffer.
// C = A[M][lda] @ BT[N][lda]^T + bias ; EPI: 0=bias, 1=bias+fast-gelu
// BM=128, BN=64, BK=64; 256 thr = 4 waves (wr=w&1, wc=w>>1), wave 64x32.
// LDS: As[2][8192] (128x64) + Bs[2][4096] (64x64) = 48KB -> 3 blocks/CU.
// ---------------------------------------------------------------------------
template<int EPI>
__global__ __launch_bounds__(256, 3) void gemm_bt(
    const u16* __restrict__ A, const u16* __restrict__ BT,
    const float* __restrict__ bias, u16* __restrict__ C,
    int M, int N, int lda, int kb) {
  __shared__ __align__(16) u16 As[2][8192];
  __shared__ __align__(16) u16 Bs[2][4096];
  const int tid = threadIdx.x;
  const int w = tid >> 6, l = tid & 63;
  const int l15 = l & 15, l4 = l >> 4;
  const int wr = w & 1, wc = w >> 1;

  // T1: XCD-chunked swizzle (guard nwg%8)
  const int gx = (int)gridDim.x, gy = (int)gridDim.y;
  int id = (int)blockIdx.y * gx + (int)blockIdx.x;
  const int nwg = gx * gy;
  if ((nwg & 7) == 0) { const int cpx = nwg >> 3; id = (id & 7) * cpx + (id >> 3); }
  const int bx = id % gx; const int by = id / gx;
  const int bm = by * 128, bn = bx * 64;

  // staging: thread -> (row srow = tid>>3 in [0,32), permuted source granule)
  const int srow = tid >> 3;
  const int sg8 = (((tid & 7) - (srow & 7)) & 7) * 8;   // logical granule at phys slot (tid&7)
  const u16* gA = A  + (size_t)(bm + srow) * lda + sg8;
  const u16* gB = BT + (size_t)(bn + srow) * lda + sg8;
  const size_t r32 = (size_t)32 * lda;
  const int sd = tid * 8;   // lane-linear LDS dest within each 32-row slab

  // fragment read offsets: row r, logical granule lg = l4 + 4*kh,
  // phys = (lg + (r&7)) & 7; offset = r*64 + phys*8
  int aOff[2][4], bOff[2][2];
  #pragma unroll
  for (int kh = 0; kh < 2; ++kh) {
    #pragma unroll
    for (int m = 0; m < 4; ++m) {
      const int r = wr * 64 + m * 16 + l15;
      aOff[kh][m] = r * 64 + (((l4 + 4 * kh) + (r & 7)) & 7) * 8;
    }
    #pragma unroll
    for (int n = 0; n < 2; ++n) {
      const int r = wc * 32 + n * 16 + l15;
      bOff[kh][n] = r * 64 + (((l4 + 4 * kh) + (r & 7)) & 7) * 8;
    }
  }

  floatx4 acc[4][2] = {};
  const int nt = kb >> 6;   // BK=64; kb in {512, 2048} -> nt in {8, 32}

  auto stage = [&](int t, int buf) {
    const u16* a = gA + (size_t)t * 64;
    const u16* b = gB + (size_t)t * 64;
    gload_lds16(a,           &As[buf][sd]);
    gload_lds16(a + r32,     &As[buf][2048 + sd]);
    gload_lds16(a + 2 * r32, &As[buf][4096 + sd]);
    gload_lds16(a + 3 * r32, &As[buf][6144 + sd]);
    gload_lds16(b,           &Bs[buf][sd]);
    gload_lds16(b + r32,     &Bs[buf][2048 + sd]);
  };

  stage(0, 0);
  asm volatile("s_waitcnt vmcnt(0)" ::: "memory");
  __builtin_amdgcn_s_barrier();
  asm volatile("" ::: "memory");

  for (int t = 0; t < nt; ++t) {
    const int cur = t & 1;
    if (t + 1 < nt) stage(t + 1, cur ^ 1);   // 6 loads overlap the whole compute phase

    #pragma unroll
    for (int kh = 0; kh < 2; ++kh) {
      short8 af[4], bf[2];
      #pragma unroll
      for (int m = 0; m < 4; ++m) af[m] = *(const short8*)(&As[cur][aOff[kh][m]]);
      #pragma unroll
      for (int n = 0; n < 2; ++n) bf[n] = *(const short8*)(&Bs[cur][bOff[kh][n]]);
      #pragma unroll
      for (int m = 0; m < 4; ++m)
        #pragma unroll
        for (int n = 0; n < 2; ++n)
          acc[m][n] = __builtin_amdgcn_mfma_f32_16x16x32_bf16(af[m], bf[n], acc[m][n], 0, 0, 0);
    }

    asm volatile("s_waitcnt vmcnt(0)" ::: "memory");
    __builtin_amdgcn_s_barrier();
    asm volatile("" ::: "memory");
  }

  // ---- epilogue ----
  const int col0 = bn + wc * 32 + l15;
  float bvv[2];
  #pragma unroll
  for (int n = 0; n < 2; ++n) bvv[n] = bias[col0 + n * 16];
  #pragma unroll
  for (int m = 0; m < 4; ++m) {
    #pragma unroll
    for (int ri = 0; ri < 4; ++ri) {
      const size_t row = (size_t)(bm + wr * 64 + m * 16 + l4 * 4 + ri);
      u16* cp = C + row * N + col0;
      #pragma unroll
      for (int n = 0; n < 2; ++n) {
        float vv = acc[m][n][ri] + bvv[n];
        if (EPI == 1) {
          // fast gelu: v * sigmoid(1.5957691 * (v + 0.044715 v^3))
          const float u = vv * (1.0f + 0.044715f * vv * vv);
          vv = vv / (1.0f + __expf(-1.5957691216057308f * u));
        }
        cp[n * 16] = f2b(vv);
      }
    }
  }
}

// ---------------------------------------------------------------------------
// Banded-Gram attention. One block per (b, 32-pos chunk, head).
// ---------------------------------------------------------------------------
#define ATL 32
#define ART (ATL + 8)   // 40 staged rows

__global__ __launch_bounds__(256) void attn_band(
    const u16* __restrict__ QKV, const float* __restrict__ bqkv,
    const float* __restrict__ bo, u16* __restrict__ newx) {
  __shared__ __align__(16) u16 S3[3][ART][72];
  __shared__ float Gb[ART][18];
  __shared__ float Sm[ART][81];
  __shared__ float Wb[ATL][9];

  const int tid = threadIdx.x;
  const int bid = ((int)blockIdx.x & 7) * 256 + ((int)blockIdx.x >> 3);
  const int h = bid & 7;
  const int chunk = (bid >> 3) & 63;
  const int b = bid >> 9;
  const int l0 = chunk * ATL;

  for (int idx = tid; idx < ART * 24; idx += 256) {
    const int ti = idx / 24, c = idx % 24;
    const int slice = c >> 3, d8 = (c & 7) * 8;
    const int col = slice * 512 + h * 64 + d8;
    const int t = l0 - 4 + ti;
    short8 v;
    if ((unsigned)t < 2048u) {
      v = *(const short8*)(QKV + ((size_t)((b << 11) | t)) * 1536 + col);
    } else {
      #pragma unroll
      for (int j = 0; j < 8; ++j) v[j] = (short)f2b(bqkv[col + j]);
    }
    *(short8*)(&S3[slice][ti][d8]) = v;
  }
  __syncthreads();

  for (int task = tid; task < ART * 17; task += 256) {
    const int ti = task / 17, j = task % 17;
    const int ui = ti + j - 8;
    if ((unsigned)ui < (unsigned)ART) {
      float a = 0.f;
      #pragma unroll
      for (int d0 = 0; d0 < 64; d0 += 8) {
        short8 qv = *(const short8*)(&S3[0][ti][d0]);
        short8 kv = *(const short8*)(&S3[1][ui][d0]);
        #pragma unroll
        for (int jj = 0; jj < 8; ++jj) a += b2f((u16)qv[jj]) * b2f((u16)kv[jj]);
      }
      Gb[ti][j] = a * 0.125f;
    }
  }
  __syncthreads();

  for (int task = tid; task < ART * 9; task += 256) {
    const int ti = task / 9, qw = task % 9;
    const int li = ti - qw;
    if ((unsigned)li < (unsigned)ATL) {
      float m = -1e30f;
      #pragma unroll
      for (int kw = 0; kw < 9; ++kw) m = fmaxf(m, Gb[ti][kw - qw + 8]);
      float e[9], s = 0.f;
      #pragma unroll
      for (int kw = 0; kw < 9; ++kw) { e[kw] = expf(Gb[ti][kw - qw + 8] - m); s += e[kw]; }
      const float inv = 1.f / s;
      #pragma unroll
      for (int kw = 0; kw < 9; ++kw) Sm[ti][qw * 9 + kw] = e[kw] * inv;
    }
  }
  __syncthreads();

  for (int task = tid; task < ATL * 9; task += 256) {
    const int li = task / 9, kw = task % 9;
    float s = 0.f;
    #pragma unroll
    for (int qw = 0; qw < 9; ++qw) s += Sm[li + qw][qw * 9 + kw];
    Wb[li][kw] = s * (1.f / 9.f);
  }
  __syncthreads();

  {
    const int li = tid >> 3, d8 = (tid & 7) * 8;
    float w[9];
    #pragma unroll
    for (int kw = 0; kw < 9; ++kw) w[kw] = Wb[li][kw];
    float a[8] = {};
    #pragma unroll
    for (int kw = 0; kw < 9; ++kw) {
      short8 vv = *(const short8*)(&S3[2][li + kw][d8]);
      #pragma unroll
      for (int jj = 0; jj < 8; ++jj) a[jj] += w[kw] * b2f((u16)vv[jj]);
    }
    short8 o;
    #pragma unroll
    for (int jj = 0; jj < 8; ++jj) o[jj] = (short)f2b(a[jj] + bo[h * 64 + d8 + jj]);
    const int l = l0 + li;
    *(short8*)(newx + ((size_t)((b << 11) | l)) * 512 + h * 64 + d8) = o;
  }
}

// ---------------------------------------------------------------------------
// LayerNorm over D=512: v = a(bf16) + b(bf16). One wave per row, 4 rows/block.
// MODE 0 -> bf16 out; MODE 1 -> fp32 out.
// ---------------------------------------------------------------------------
template<int MODE>
__global__ __launch_bounds__(256) void ln_kernel(
    const u16* __restrict__ a, const u16* __restrict__ bsrc,
    const float* __restrict__ g, const float* __restrict__ be,
    u16* __restrict__ outb, float* __restrict__ outf) {
  const int wave = threadIdx.x >> 6, lane = threadIdx.x & 63;
  const size_t row = (size_t)blockIdx.x * 4 + wave;
  const size_t base = row * 512 + lane * 8;
  const int gi = lane * 8;
  float v[8];
  short8 a8 = *(const short8*)(a + base);
  short8 b8 = *(const short8*)(bsrc + base);
  #pragma unroll
  for (int j = 0; j < 8; ++j) v[j] = b2f((u16)a8[j]) + b2f((u16)b8[j]);

  float s = 0.f;
  #pragma unroll
  for (int j = 0; j < 8; ++j) s += v[j];
  #pragma unroll
  for (int off = 32; off >= 1; off >>= 1) s += __shfl_xor(s, off, 64);
  const float mean = s * (1.f / 512.f);
  float sq = 0.f;
  #pragma unroll
  for (int j = 0; j < 8; ++j) { float d = v[j] - mean; sq += d * d; }
  #pragma unroll
  for (int off = 32; off >= 1; off >>= 1) sq += __shfl_xor(sq, off, 64);
  const float rs = rsqrtf(sq * (1.f / 512.f) + 1e-5f);

  if (MODE == 0) {
    short8 o;
    #pragma unroll
    for (int j = 0; j < 8; ++j)
      o[j] = (short)f2b((v[j] - mean) * rs * g[gi + j] + be[gi + j]);
    *(short8*)(outb + base) = o;
  } else {
    float4 o0, o1;
    o0.x = (v[0] - mean) * rs * g[gi + 0] + be[gi + 0];
    o0.y = (v[1] - mean) * rs * g[gi + 1] + be[gi + 1];
    o0.z = (v[2] - mean) * rs * g[gi + 2] + be[gi + 2];
    o0.w = (v[3] - mean) * rs * g[gi + 3] + be[gi + 3];
    o1.x = (v[4] - mean) * rs * g[gi + 4] + be[gi + 4];
    o1.y = (v[5] - mean) * rs * g[gi + 5] + be[gi + 5];
    o1.z = (v[6] - mean) * rs * g[gi + 6] + be[gi + 6];
    o1.w = (v[7] - mean) * rs * g[gi + 7] + be[gi + 7];
    *(float4*)(outf + base) = o0;
    *(float4*)(outf + base + 4) = o1;
  }
}

// ---------------------------------------------------------------------------
extern "C" void kernel_launch(void* const* d_in, const int* in_sizes, int n_in,
                              void* d_out, int out_size, void* d_ws, size_t ws_size,
                              hipStream_t stream) {
  const float* x   = (const float*)d_in[0];
  const float* Wq  = (const float*)d_in[1];
  const float* bq  = (const float*)d_in[2];
  const float* Wk  = (const float*)d_in[3];
  const float* bk  = (const float*)d_in[4];
  const float* Wv  = (const float*)d_in[5];
  const float* bv  = (const float*)d_in[6];
  const float* Wo  = (const float*)d_in[7];
  const float* bo  = (const float*)d_in[8];
  const float* W1  = (const float*)d_in[9];
  const float* b1  = (const float*)d_in[10];
  const float* W2  = (const float*)d_in[11];
  const float* b2  = (const float*)d_in[12];
  const float* g1  = (const float*)d_in[13];
  const float* be1 = (const float*)d_in[14];
  const float* g2  = (const float*)d_in[15];
  const float* be2 = (const float*)d_in[16];

  char* w = (char*)d_ws;
  u16*   xb    = (u16*)  (w + 0);           // 8 MB
  u16*   WqkvT = (u16*)  (w + 8388608);     // [1536][512] bf16 (q,k,vo)
  u16*   WoT   = (u16*)  (w + 9961472);     // [512][512] bf16 Wo^T
  u16*   W1T   = (u16*)  (w + 10485760);    // [2048][512]
  u16*   W2T   = (u16*)  (w + 12582912);    // [512][2048]
  float* bqkv  = (float*)(w + 14680064);    // 2048 f32 (bq,bk,bvo,zeros)
  u16*   Wvb   = (u16*)  (w + 14688256);    // [512][512] bf16 row-major Wv
  u16*   QKV   = (u16*)  (w + 15212544);    // 8192x1536 bf16 (dead after attn)
  u16*   hbuf  = QKV;                       // 8192x2048 bf16 (aliases QKV)
  u16*   newx  = (u16*)  (w + 48766976);    // 8192x512 bf16; ybuf after LN1
  u16*   x1b   = (u16*)  (w + 57155584);    // 8192x512 bf16
  u16*   WvoT  = WqkvT + 524288;            // V region of WqkvT = (Wv@Wo)^T
  u16*   ybuf  = newx;                      // G4 output (b2 included)

  // --- prep (single dispatch: transposes + bias + x->bf16) ---
  prep_all<<<7176, 256, 0, stream>>>(Wq, Wk, Wo, W1, W2, Wv, bq, bk, bv, x,
                                     WqkvT, WoT, W1T, W2T, Wvb, bqkv, xb);
  // --- WvoT = (Wv@Wo)^T via MFMA GEMM: C[n][k] = sum_j WoT[n][j]*Wvb[k][j] ---
  gemm_bt<0><<<dim3(8, 4), 256, 0, stream>>>(WoT, Wvb, bqkv + 1536, WvoT,
                                             512, 512, 512, 512);
  // --- G1: QKV'' ---
  gemm_bt<0><<<dim3(24, 64), 256, 0, stream>>>(xb, WqkvT, bqkv, QKV,
                                               8192, 1536, 512, 512);
  // --- attention (banded Gram) -> newx ---
  attn_band<<<2048, 256, 0, stream>>>(QKV, bqkv, bo, newx);
  // --- LN1: x1 = LN(xb + newx) ---
  ln_kernel<0><<<2048, 256, 0, stream>>>(xb, newx, g1, be1, x1b, nullptr);
  // --- G3: h = gelu(x1 @ W1T^T + b1) ---
  gemm_bt<1><<<dim3(32, 64), 256, 0, stream>>>(x1b, W1T, b1, hbuf,
                                               8192, 2048, 512, 512);
  // --- G4: y = h @ W2T^T + b2 (unsplit, K=2048) ---
  gemm_bt<0><<<dim3(8, 64), 256, 0, stream>>>(hbuf, W2T, b2, ybuf,
                                              8192, 512, 2048, 2048);
  // --- LN2 -> out ---
  ln_kernel<1><<<2048, 256, 0, stream>>>(x1b, ybuf, g2, be2, nullptr, (float*)d_out);
}

// Round 17
// 142.892 us; speedup vs baseline: 1.3372x; 1.0198x over previous
//
#include <hip/hip_runtime.h>

// ---------------------------------------------------------------------------
// LocalWindowAttentionLayer on MI355X (gfx950)
// B=4 L=2048 D=512 H=8 DK=64 DF=2048 W=9
//
// Pipeline (G2 folded into G1 via Wvo = Wv@Wo):
//  prep: transposes + bias + x->bf16 in ONE dispatch
//  Wvo: WvoT = gemm(WoT, Wvb)
//  G1 : QKV'' = xb @ [Wq;Wk;Wvo]^T + [bq;bk;bvo]   (8192 x 1536, K=512)
//  A  : banded-Gram attention -> newx (8192 x 512)
//  LN1: x1 = LN(xb + newx)
//  G3 : h = gelu(x1 @ W1T^T + b1)       (8192 x 2048, K=512)  [fast gelu]
//  G4 : y partials (split-K=2)          (8192 x 512,  K=2048)
//  LN2: out = LN(x1 + y0 + y1 + b2) -> fp32
//
// gemm (R17): 128x128 tile, BK=32 — the untested cell of the tile x schedule
// matrix. Staged-bytes factor (1/BM+1/BN) drops 33% vs R13's 128x64 while
// keeping >=4 blocks/CU (R14/R9 failures were occupancy violations, not
// tile size per se). Geometry = R2's verified 2x2-wave 64x64 fragments
// (acc[4][4]); staging/permute/schedule = R13's verified pieces (stage(t+1)
// issued before compute, vmcnt(0)+barrier per tile, 4-granule XOR permute,
// XCD-chunked swizzle). LDS 2x(8K+8K)=32KB; ~116 regs; launch_bounds(256,4).
// ---------------------------------------------------------------------------

typedef unsigned short u16;
typedef __attribute__((ext_vector_type(8))) short short8;   // 8 bf16
typedef __attribute__((ext_vector_type(4))) float floatx4;  // MFMA acc

#define DEV static __device__ __forceinline__

DEV float b2f(u16 u) {
  union { unsigned int i; float f; } x; x.i = ((unsigned int)u) << 16; return x.f;
}
DEV u16 f2b(float f) {  // round-to-nearest-even
  union { float f; unsigned int i; } x; x.f = f;
  unsigned int u = x.i + 0x7fffu + ((x.i >> 16) & 1u);
  return (u16)(u >> 16);
}

#define AS1 __attribute__((address_space(1)))
#define AS3 __attribute__((address_space(3)))
DEV void gload_lds16(const void* g, void* l) {
  __builtin_amdgcn_global_load_lds((const AS1 void*)g, (AS3 void*)l, 16, 0, 0);
}

// ---------------------------------------------------------------------------
// Fused prep, one dispatch:
//  [0,3072)    : transposes (fp32 RxC -> bf16 CxR) Wq,Wk,Wo,W1,W2 + Wv copy
//  [3072,3080) : bias vector prep (bq | bk | bvo = bv@Wo | zeros)
//  [3080,7176) : x fp32 -> bf16 (float4 granules)
// ---------------------------------------------------------------------------
__global__ __launch_bounds__(256) void prep_all(
    const float* __restrict__ Wq, const float* __restrict__ Wk,
    const float* __restrict__ Wo, const float* __restrict__ W1,
    const float* __restrict__ W2, const float* __restrict__ Wv,
    const float* __restrict__ bq, const float* __restrict__ bk,
    const float* __restrict__ bv, const float* __restrict__ x,
    u16* __restrict__ WqkvT, u16* __restrict__ WoT,
    u16* __restrict__ W1T, u16* __restrict__ W2T, u16* __restrict__ Wvb,
    float* __restrict__ bqkv, u16* __restrict__ xb) {
  const int bid = blockIdx.x;
  if (bid >= 3080) {  // x f2b
    const int i = (bid - 3080) * 256 + threadIdx.x;
    float4 v = ((const float4*)x)[i];
    ushort4 o;
    o.x = f2b(v.x); o.y = f2b(v.y); o.z = f2b(v.z); o.w = f2b(v.w);
    ((ushort4*)xb)[i] = o;
    return;
  }
  if (bid >= 3072) {  // bias prep
    const int i = (bid - 3072) * 256 + threadIdx.x;
    if (i < 512) bqkv[i] = bq[i];
    else if (i < 1024) bqkv[i] = bk[i - 512];
    else if (i < 1536) {
      const int c = i - 1024;
      float s = 0.f;
      for (int j = 0; j < 512; ++j) s += bv[j] * Wo[(size_t)j * 512 + c];
      bqkv[i] = s;
    } else bqkv[i] = 0.f;
    return;
  }
  if (bid >= 2816) {  // Wv f2b copy (512x512)
    const int i = (bid - 2816) * 256 + threadIdx.x;
    float4 v = ((const float4*)Wv)[i];
    ushort4 o;
    o.x = f2b(v.x); o.y = f2b(v.y); o.z = f2b(v.z); o.w = f2b(v.w);
    ((ushort4*)Wvb)[i] = o;
    return;
  }
  const float* in; u16* out; int R, C, t;
  if (bid < 256)       { in = Wq; out = WqkvT;          R = 512;  C = 512;  t = bid; }
  else if (bid < 512)  { in = Wk; out = WqkvT + 262144; R = 512;  C = 512;  t = bid - 256; }
  else if (bid < 768)  { in = Wo; out = WoT;            R = 512;  C = 512;  t = bid - 512; }
  else if (bid < 1792) { in = W1; out = W1T;            R = 512;  C = 2048; t = bid - 768; }
  else                 { in = W2; out = W2T;            R = 2048; C = 512;  t = bid - 1792; }
  const int tpr = C >> 5;
  const int bc = (t % tpr) * 32, br = (t / tpr) * 32;
  __shared__ float tile[32][33];
  const int tx = threadIdx.x & 31, ty = threadIdx.x >> 5;
  #pragma unroll
  for (int i = 0; i < 32; i += 8)
    tile[ty + i][tx] = in[(size_t)(br + ty + i) * C + bc + tx];
  __syncthreads();
  #pragma unroll
  for (int i = 0; i < 32; i += 8)
    out[(size_t)(bc + ty + i) * R + br + tx] = f2b(tile[tx][ty + i]);
}

// ---------------------------------------------------------------------------
// bf16 MFMA GEMM, 128x128 tile, BK=32, R13 schedule.
// C = A[M][lda] @ BT[N][lda]^T + bias
// EPI: 0=bias->bf16, 1=bias+fast-gelu->bf16, 2=raw bf16 partial (split-K z)
// 256 thr = 4 waves (wm=(w>>1)*64, wn=(w&1)*64), wave 64x64 -> acc[4][4]
// (R2-verified fragment geometry). LDS As[2][4096]+Bs[2][4096] = 32KB.
// Staging: 4 gload_lds/thread/tile (A rows tid>>2 +{0,64}, B same), permuted
// source granule; read phys slot = (l4 + ((l15>>1)&3)) & 3 (R7+ involution).
// ---------------------------------------------------------------------------
template<int EPI>
__global__ __launch_bounds__(256, 4) void gemm_bt(
    const u16* __restrict__ A, const u16* __restrict__ BT,
    const float* __restrict__ bias, u16* __restrict__ C, u16* __restrict__ C2,
    int M, int N, int lda, int kb) {
  __shared__ __align__(16) u16 As[2][4096];
  __shared__ __align__(16) u16 Bs[2][4096];
  const int tid = threadIdx.x;
  const int w = tid >> 6, l = tid & 63;
  const int l15 = l & 15, l4 = l >> 4;
  const int wm = (w >> 1) * 64, wn = (w & 1) * 64;

  // T1: XCD-chunked swizzle over flattened 3D grid (guard nwg%8)
  const int gx = (int)gridDim.x, gy = (int)gridDim.y;
  int id = ((int)blockIdx.z * gy + (int)blockIdx.y) * gx + (int)blockIdx.x;
  const int nwg = gx * gy * (int)gridDim.z;
  if ((nwg & 7) == 0) { const int cpx = nwg >> 3; id = (id & 7) * cpx + (id >> 3); }
  const int bx = id % gx; const int r1 = id / gx;
  const int by = r1 % gy; const int bz = r1 / gy;
  const int bm = by * 128, bn = bx * 128;
  const int koff = bz * kb;

  // staging: thread -> (row0 = tid>>2 in [0,64), permuted source granule)
  const int row0 = tid >> 2;
  const int kc0 = ((((tid & 3) - ((tid >> 3) & 3)) & 3)) * 8;
  const u16* gA = A  + (size_t)(bm + row0) * lda + koff + kc0;
  const u16* gB = BT + (size_t)(bn + row0) * lda + koff + kc0;
  const size_t r64 = (size_t)64 * lda;
  const int sd = tid * 8;   // linear LDS dest within each 64-row slab (2048 elems)

  // fragment read offsets: row r = base16 + l15, phys granule = (l4+((l15>>1)&3))&3
  const int rg8 = ((l4 + ((l15 >> 1) & 3)) & 3) * 8;
  int aOff[4], bOff[4];
  #pragma unroll
  for (int i = 0; i < 4; ++i) {
    aOff[i] = (wm + i * 16 + l15) * 32 + rg8;
    bOff[i] = (wn + i * 16 + l15) * 32 + rg8;
  }

  floatx4 acc[4][4] = {};
  const int nt = kb >> 5;

  auto stage = [&](int t, int buf) {
    const u16* a = gA + (size_t)t * 32;
    const u16* b = gB + (size_t)t * 32;
    gload_lds16(a,       &As[buf][sd]);
    gload_lds16(a + r64, &As[buf][2048 + sd]);
    gload_lds16(b,       &Bs[buf][sd]);
    gload_lds16(b + r64, &Bs[buf][2048 + sd]);
  };

  stage(0, 0);
  asm volatile("s_waitcnt vmcnt(0)" ::: "memory");
  __builtin_amdgcn_s_barrier();
  asm volatile("" ::: "memory");

  for (int t = 0; t < nt; ++t) {
    const int cur = t & 1;
    if (t + 1 < nt) stage(t + 1, cur ^ 1);   // 4 loads overlap the compute phase

    short8 af[4], bf[4];
    #pragma unroll
    for (int i = 0; i < 4; ++i) {
      af[i] = *(const short8*)(&As[cur][aOff[i]]);
      bf[i] = *(const short8*)(&Bs[cur][bOff[i]]);
    }
    #pragma unroll
    for (int i = 0; i < 4; ++i)
      #pragma unroll
      for (int j = 0; j < 4; ++j)
        acc[i][j] = __builtin_amdgcn_mfma_f32_16x16x32_bf16(af[i], bf[j], acc[i][j], 0, 0, 0);

    asm volatile("s_waitcnt vmcnt(0)" ::: "memory");
    __builtin_amdgcn_s_barrier();
    asm volatile("" ::: "memory");
  }

  // ---- epilogue (R2-verified mapping: row = bm+wm+i*16+l4*4+r, col = bn+wn+j*16+l15) ----
  const int col0 = bn + wn + l15;
  if (EPI <= 1) {
    float bvv[4];
    #pragma unroll
    for (int j = 0; j < 4; ++j) bvv[j] = bias[col0 + j * 16];
    #pragma unroll
    for (int i = 0; i < 4; ++i) {
      #pragma unroll
      for (int r = 0; r < 4; ++r) {
        const size_t row = (size_t)(bm + wm + i * 16 + l4 * 4 + r);
        u16* cp = C + row * N + col0;
        #pragma unroll
        for (int j = 0; j < 4; ++j) {
          float vv = acc[i][j][r] + bvv[j];
          if (EPI == 1) {
            // fast gelu: v * sigmoid(1.5957691 * (v + 0.044715 v^3))
            const float u = vv * (1.0f + 0.044715f * vv * vv);
            vv = vv / (1.0f + __expf(-1.5957691216057308f * u));
          }
          cp[j * 16] = f2b(vv);
        }
      }
    }
  } else {
    u16* o = (bz == 0) ? C : C2;
    #pragma unroll
    for (int i = 0; i < 4; ++i) {
      #pragma unroll
      for (int r = 0; r < 4; ++r) {
        const size_t row = (size_t)(bm + wm + i * 16 + l4 * 4 + r);
        u16* cp = o + row * N + col0;
        #pragma unroll
        for (int j = 0; j < 4; ++j) cp[j * 16] = f2b(acc[i][j][r]);
      }
    }
  }
}

// ---------------------------------------------------------------------------
// Banded-Gram attention. One block per (b, 32-pos chunk, head).
// ---------------------------------------------------------------------------
#define ATL 32
#define ART (ATL + 8)   // 40 staged rows

__global__ __launch_bounds__(256) void attn_band(
    const u16* __restrict__ QKV, const float* __restrict__ bqkv,
    const float* __restrict__ bo, u16* __restrict__ newx) {
  __shared__ __align__(16) u16 S3[3][ART][72];
  __shared__ float Gb[ART][18];
  __shared__ float Sm[ART][81];
  __shared__ float Wb[ATL][9];

  const int tid = threadIdx.x;
  const int bid = ((int)blockIdx.x & 7) * 256 + ((int)blockIdx.x >> 3);
  const int h = bid & 7;
  const int chunk = (bid >> 3) & 63;
  const int b = bid >> 9;
  const int l0 = chunk * ATL;

  for (int idx = tid; idx < ART * 24; idx += 256) {
    const int ti = idx / 24, c = idx % 24;
    const int slice = c >> 3, d8 = (c & 7) * 8;
    const int col = slice * 512 + h * 64 + d8;
    const int t = l0 - 4 + ti;
    short8 v;
    if ((unsigned)t < 2048u) {
      v = *(const short8*)(QKV + ((size_t)((b << 11) | t)) * 1536 + col);
    } else {
      #pragma unroll
      for (int j = 0; j < 8; ++j) v[j] = (short)f2b(bqkv[col + j]);
    }
    *(short8*)(&S3[slice][ti][d8]) = v;
  }
  __syncthreads();

  for (int task = tid; task < ART * 17; task += 256) {
    const int ti = task / 17, j = task % 17;
    const int ui = ti + j - 8;
    if ((unsigned)ui < (unsigned)ART) {
      float a = 0.f;
      #pragma unroll
      for (int d0 = 0; d0 < 64; d0 += 8) {
        short8 qv = *(const short8*)(&S3[0][ti][d0]);
        short8 kv = *(const short8*)(&S3[1][ui][d0]);
        #pragma unroll
        for (int jj = 0; jj < 8; ++jj) a += b2f((u16)qv[jj]) * b2f((u16)kv[jj]);
      }
      Gb[ti][j] = a * 0.125f;
    }
  }
  __syncthreads();

  for (int task = tid; task < ART * 9; task += 256) {
    const int ti = task / 9, qw = task % 9;
    const int li = ti - qw;
    if ((unsigned)li < (unsigned)ATL) {
      float m = -1e30f;
      #pragma unroll
      for (int kw = 0; kw < 9; ++kw) m = fmaxf(m, Gb[ti][kw - qw + 8]);
      float e[9], s = 0.f;
      #pragma unroll
      for (int kw = 0; kw < 9; ++kw) { e[kw] = expf(Gb[ti][kw - qw + 8] - m); s += e[kw]; }
      const float inv = 1.f / s;
      #pragma unroll
      for (int kw = 0; kw < 9; ++kw) Sm[ti][qw * 9 + kw] = e[kw] * inv;
    }
  }
  __syncthreads();

  for (int task = tid; task < ATL * 9; task += 256) {
    const int li = task / 9, kw = task % 9;
    float s = 0.f;
    #pragma unroll
    for (int qw = 0; qw < 9; ++qw) s += Sm[li + qw][qw * 9 + kw];
    Wb[li][kw] = s * (1.f / 9.f);
  }
  __syncthreads();

  {
    const int li = tid >> 3, d8 = (tid & 7) * 8;
    float w[9];
    #pragma unroll
    for (int kw = 0; kw < 9; ++kw) w[kw] = Wb[li][kw];
    float a[8] = {};
    #pragma unroll
    for (int kw = 0; kw < 9; ++kw) {
      short8 vv = *(const short8*)(&S3[2][li + kw][d8]);
      #pragma unroll
      for (int jj = 0; jj < 8; ++jj) a[jj] += w[kw] * b2f((u16)vv[jj]);
    }
    short8 o;
    #pragma unroll
    for (int jj = 0; jj < 8; ++jj) o[jj] = (short)f2b(a[jj] + bo[h * 64 + d8 + jj]);
    const int l = l0 + li;
    *(short8*)(newx + ((size_t)((b << 11) | l)) * 512 + h * 64 + d8) = o;
  }
}

// ---------------------------------------------------------------------------
// LayerNorm over D=512. One wave per row, 4 rows/block.
// MODE 0: v = a + b                  -> bf16 out
// MODE 1: v = a + b + c + bias[col]  -> fp32 out
// ---------------------------------------------------------------------------
template<int MODE>
__global__ __launch_bounds__(256) void ln_kernel(
    const u16* __restrict__ a, const u16* __restrict__ bsrc,
    const u16* __restrict__ csrc, const float* __restrict__ bias,
    const float* __restrict__ g, const float* __restrict__ be,
    u16* __restrict__ outb, float* __restrict__ outf) {
  const int wave = threadIdx.x >> 6, lane = threadIdx.x & 63;
  const size_t row = (size_t)blockIdx.x * 4 + wave;
  const size_t base = row * 512 + lane * 8;
  const int gi = lane * 8;
  float v[8];
  short8 a8 = *(const short8*)(a + base);
  short8 b8 = *(const short8*)(bsrc + base);
  #pragma unroll
  for (int j = 0; j < 8; ++j) v[j] = b2f((u16)a8[j]) + b2f((u16)b8[j]);
  if (MODE == 1) {
    short8 c8 = *(const short8*)(csrc + base);
    #pragma unroll
    for (int j = 0; j < 8; ++j) v[j] += b2f((u16)c8[j]) + bias[gi + j];
  }

  float s = 0.f;
  #pragma unroll
  for (int j = 0; j < 8; ++j) s += v[j];
  #pragma unroll
  for (int off = 32; off >= 1; off >>= 1) s += __shfl_xor(s, off, 64);
  const float mean = s * (1.f / 512.f);
  float sq = 0.f;
  #pragma unroll
  for (int j = 0; j < 8; ++j) { float d = v[j] - mean; sq += d * d; }
  #pragma unroll
  for (int off = 32; off >= 1; off >>= 1) sq += __shfl_xor(sq, off, 64);
  const float rs = rsqrtf(sq * (1.f / 512.f) + 1e-5f);

  if (MODE == 0) {
    short8 o;
    #pragma unroll
    for (int j = 0; j < 8; ++j)
      o[j] = (short)f2b((v[j] - mean) * rs * g[gi + j] + be[gi + j]);
    *(short8*)(outb + base) = o;
  } else {
    float4 o0, o1;
    o0.x = (v[0] - mean) * rs * g[gi + 0] + be[gi + 0];
    o0.y = (v[1] - mean) * rs * g[gi + 1] + be[gi + 1];
    o0.z = (v[2] - mean) * rs * g[gi + 2] + be[gi + 2];
    o0.w = (v[3] - mean) * rs * g[gi + 3] + be[gi + 3];
    o1.x = (v[4] - mean) * rs * g[gi + 4] + be[gi + 4];
    o1.y = (v[5] - mean) * rs * g[gi + 5] + be[gi + 5];
    o1.z = (v[6] - mean) * rs * g[gi + 6] + be[gi + 6];
    o1.w = (v[7] - mean) * rs * g[gi + 7] + be[gi + 7];
    *(float4*)(outf + base) = o0;
    *(float4*)(outf + base + 4) = o1;
  }
}

// ---------------------------------------------------------------------------
extern "C" void kernel_launch(void* const* d_in, const int* in_sizes, int n_in,
                              void* d_out, int out_size, void* d_ws, size_t ws_size,
                              hipStream_t stream) {
  const float* x   = (const float*)d_in[0];
  const float* Wq  = (const float*)d_in[1];
  const float* bq  = (const float*)d_in[2];
  const float* Wk  = (const float*)d_in[3];
  const float* bk  = (const float*)d_in[4];
  const float* Wv  = (const float*)d_in[5];
  const float* bv  = (const float*)d_in[6];
  const float* Wo  = (const float*)d_in[7];
  const float* bo  = (const float*)d_in[8];
  const float* W1  = (const float*)d_in[9];
  const float* b1  = (const float*)d_in[10];
  const float* W2  = (const float*)d_in[11];
  const float* b2  = (const float*)d_in[12];
  const float* g1  = (const float*)d_in[13];
  const float* be1 = (const float*)d_in[14];
  const float* g2  = (const float*)d_in[15];
  const float* be2 = (const float*)d_in[16];

  char* w = (char*)d_ws;
  u16*   xb    = (u16*)  (w + 0);           // 8 MB; yp1 after LN1
  u16*   WqkvT = (u16*)  (w + 8388608);     // [1536][512] bf16 (q,k,vo)
  u16*   WoT   = (u16*)  (w + 9961472);     // [512][512] bf16 Wo^T
  u16*   W1T   = (u16*)  (w + 10485760);    // [2048][512]
  u16*   W2T   = (u16*)  (w + 12582912);    // [512][2048]
  float* bqkv  = (float*)(w + 14680064);    // 2048 f32 (bq,bk,bvo,zeros)
  u16*   Wvb   = (u16*)  (w + 14688256);    // [512][512] bf16 row-major Wv
  u16*   QKV   = (u16*)  (w + 15212544);    // 8192x1536 bf16 (dead after attn)
  u16*   hbuf  = QKV;                       // 8192x2048 bf16 (aliases QKV)
  u16*   newx  = (u16*)  (w + 48766976);    // 8192x512 bf16; yp0 after LN1
  u16*   x1b   = (u16*)  (w + 57155584);    // 8192x512 bf16
  u16*   WvoT  = WqkvT + 524288;            // V region of WqkvT = (Wv@Wo)^T
  u16*   yp0   = newx;                      // G4 split-K partial z=0
  u16*   yp1   = xb;                        // G4 split-K partial z=1

  // --- prep (single dispatch: transposes + bias + x->bf16) ---
  prep_all<<<7176, 256, 0, stream>>>(Wq, Wk, Wo, W1, W2, Wv, bq, bk, bv, x,
                                     WqkvT, WoT, W1T, W2T, Wvb, bqkv, xb);
  // --- WvoT = (Wv@Wo)^T via MFMA GEMM: C[n][k] = sum_j WoT[n][j]*Wvb[k][j] ---
  gemm_bt<0><<<dim3(4, 4, 1), 256, 0, stream>>>(WoT, Wvb, bqkv + 1536, WvoT, nullptr,
                                                512, 512, 512, 512);
  // --- G1: QKV'' ---
  gemm_bt<0><<<dim3(12, 64, 1), 256, 0, stream>>>(xb, WqkvT, bqkv, QKV, nullptr,
                                                  8192, 1536, 512, 512);
  // --- attention (banded Gram) -> newx ---
  attn_band<<<2048, 256, 0, stream>>>(QKV, bqkv, bo, newx);
  // --- LN1: x1 = LN(xb + newx) ---
  ln_kernel<0><<<2048, 256, 0, stream>>>(xb, newx, nullptr, nullptr, g1, be1, x1b, nullptr);
  // --- G3: h = gelu(x1 @ W1T^T + b1) ---
  gemm_bt<1><<<dim3(16, 64, 1), 256, 0, stream>>>(x1b, W1T, b1, hbuf, nullptr,
                                                  8192, 2048, 512, 512);
  // --- G4: y partials (split-K=2, K=1024 each) ---
  gemm_bt<2><<<dim3(4, 64, 2), 256, 0, stream>>>(hbuf, W2T, nullptr, yp0, yp1,
                                                 8192, 512, 2048, 1024);
  // --- LN2 -> out ---
  ln_kernel<1><<<2048, 256, 0, stream>>>(x1b, yp0, yp1, b2, g2, be2, nullptr, (float*)d_out);
}